// Round 1
// baseline (288.334 us; speedup 1.0000x reference)
//
#include <hip/hip_runtime.h>
#include <hip/hip_bf16.h>
#include <stdint.h>

#define BN 8192
#define DK 1024
#define NCHUNK 8          // 8 column chunks of 1024
#define CHUNK_COLS 1024

typedef __attribute__((ext_vector_type(8))) short bf16x8;   // 8 bf16 (4 VGPRs)
typedef __attribute__((ext_vector_type(4))) float f32x4;

__device__ __forceinline__ unsigned short f2bf(float f) {
  // round-to-nearest-even fp32 -> bf16
  unsigned int u = __float_as_uint(f);
  return (unsigned short)((u + 0x7fffu + ((u >> 16) & 1u)) >> 16);
}

// ---------------- prep: bf16 copy of x + fp32 row norms ----------------
// one wave per row, 4 waves per block, grid = 8192/4
__global__ __launch_bounds__(256) void snn_prep(const float* __restrict__ x,
                                                unsigned short* __restrict__ xb,
                                                float* __restrict__ xn) {
  const int row = blockIdx.x * 4 + (threadIdx.x >> 6);
  const int lane = threadIdx.x & 63;
  const float4* src = (const float4*)(x + (size_t)row * DK);
  ushort4* dst = (ushort4*)(xb + (size_t)row * DK);
  float s = 0.f;
#pragma unroll
  for (int i = 0; i < 4; ++i) {
    float4 v = src[lane + i * 64];
    s = fmaf(v.x, v.x, s); s = fmaf(v.y, v.y, s);
    s = fmaf(v.z, v.z, s); s = fmaf(v.w, v.w, s);
    ushort4 o;
    o.x = f2bf(v.x); o.y = f2bf(v.y); o.z = f2bf(v.z); o.w = f2bf(v.w);
    dst[lane + i * 64] = o;
  }
#pragma unroll
  for (int m = 32; m >= 1; m >>= 1) s += __shfl_xor(s, m);
  if (lane == 0) xn[row] = s;
}

// ---------------- main: fused Gram + masked online logsumexp ----------------
// grid (NCHUNK, BN/128); block 256 (4 waves in 2x2 over a 128x128 tile)
__global__ __launch_bounds__(256, 2) void snn_main(
    const unsigned short* __restrict__ xb, const float* __restrict__ xn,
    const int* __restrict__ y, const unsigned int* __restrict__ Tp,
    float* __restrict__ part) {
  __shared__ __align__(16) unsigned short As[128 * 64];  // XOR-swizzled
  __shared__ __align__(16) unsigned short Bs[128 * 64];
  __shared__ float stM[2][128], stD[2][128], stN[2][128];
  __shared__ float xnA[128], xnB[128];
  __shared__ int yA[128], yB[128];

  const int t = threadIdx.x;
  const int lane = t & 63;
  const int w = t >> 6;
  const int wr = w >> 1, wc = w & 1;
  const int l15 = lane & 15;
  const int lg = lane >> 4;

  const int chunk = blockIdx.x;
  const int rt = blockIdx.y;
  const int r0 = rt * 128;
  const int c0 = chunk * CHUNK_COLS;

  // T arrives as a 1-elem array; tolerate int32/int64/float32 encodings.
  const unsigned int tu = *Tp;
  const float tf = (tu & 0x7f800000u) ? __uint_as_float(tu) : (float)(int)tu;

  if (t < 128) {
    xnA[t] = xn[r0 + t];
    yA[t] = y[r0 + t];
    stM[0][t] = -__builtin_inff(); stM[1][t] = -__builtin_inff();
    stD[0][t] = 0.f; stD[1][t] = 0.f;
    stN[0][t] = 0.f; stN[1][t] = 0.f;
  }

  for (int jt = 0; jt < 8; ++jt) {
    const int cb = c0 + jt * 128;
    __syncthreads();  // prev epilogue / init visible, LDS reusable
    if (t < 128) { xnB[t] = xn[cb + t]; yB[t] = y[cb + t]; }

    f32x4 acc[4][4];
#pragma unroll
    for (int mi = 0; mi < 4; ++mi)
#pragma unroll
      for (int ni = 0; ni < 4; ++ni) acc[mi][ni] = (f32x4){0.f, 0.f, 0.f, 0.f};

    for (int kt = 0; kt < DK; kt += 64) {
      // stage A(128x64) and B(128x64) via global_load_lds, width 16.
      // LDS dest is linear (base + lane*16); swizzle applied on the GLOBAL
      // source: physical chunk cg holds logical chunk cg^(row&7).
#pragma unroll
      for (int i = 0; i < 4; ++i) {
        int linear = i * 256 + t;       // 0..1023
        int row = linear >> 3;          // 0..127
        int cg = linear & 7;            // physical 16B chunk
        int cl = cg ^ (row & 7);        // logical chunk (pre-swizzled source)
        const unsigned short* sa = xb + (size_t)(r0 + row) * DK + kt + cl * 8;
        const unsigned short* sb = xb + (size_t)(cb + row) * DK + kt + cl * 8;
        __builtin_amdgcn_global_load_lds(
            (const __attribute__((address_space(1))) void*)sa,
            (__attribute__((address_space(3))) void*)((char*)As + linear * 16),
            16, 0, 0);
        __builtin_amdgcn_global_load_lds(
            (const __attribute__((address_space(1))) void*)sb,
            (__attribute__((address_space(3))) void*)((char*)Bs + linear * 16),
            16, 0, 0);
      }
      __syncthreads();
#pragma unroll
      for (int kk = 0; kk < 2; ++kk) {
        bf16x8 af[4], bfv[4];
        const int colb = kk * 64 + lg * 16;  // logical byte offset in row
#pragma unroll
        for (int mi = 0; mi < 4; ++mi) {
          int row = wr * 64 + mi * 16 + l15;
          af[mi] = *(const bf16x8*)((const char*)As + row * 128 +
                                    (colb ^ ((row & 7) << 4)));
        }
#pragma unroll
        for (int ni = 0; ni < 4; ++ni) {
          int row = wc * 64 + ni * 16 + l15;
          bfv[ni] = *(const bf16x8*)((const char*)Bs + row * 128 +
                                     (colb ^ ((row & 7) << 4)));
        }
#pragma unroll
        for (int mi = 0; mi < 4; ++mi)
#pragma unroll
          for (int ni = 0; ni < 4; ++ni)
            acc[mi][ni] = __builtin_amdgcn_mfma_f32_16x16x32_bf16(
                af[mi], bfv[ni], acc[mi][ni], 0, 0, 0);
      }
      __syncthreads();
    }

    // ---- epilogue: e = -sqrt(max(xn_r + xn_c - 2*dot, 0)) * T ----
    // C layout: col = lane&15 (+ni*16+wc*64), row = (lane>>4)*4+reg (+mi*16+wr*64)
#pragma unroll
    for (int mi = 0; mi < 4; ++mi) {
#pragma unroll
      for (int rg = 0; rg < 4; ++rg) {
        const int row_l = wr * 64 + mi * 16 + lg * 4 + rg;
        const int rG = r0 + row_l;
        const float rxn = xnA[row_l];
        const int ry = yA[row_l];
        float ev[4];
        bool vv[4], sv[4];
        float mloc = -__builtin_inff();
#pragma unroll
        for (int ni = 0; ni < 4; ++ni) {
          int c_l = wc * 64 + ni * 16 + l15;
          int cG = cb + c_l;
          float a = acc[mi][ni][rg];
          float d2 = fmaxf(rxn + xnB[c_l] - 2.0f * a, 0.f);
          float e = -sqrtf(d2) * tf;
          bool v = (rG != cG);
          ev[ni] = e; vv[ni] = v;
          sv[ni] = v && (ry == yB[c_l]);
          if (v) mloc = fmaxf(mloc, e);
        }
        // 16-lane butterfly max over the row's 64 cols in this wave
#pragma unroll
        for (int m = 8; m >= 1; m >>= 1) mloc = fmaxf(mloc, __shfl_xor(mloc, m));
        float sd = 0.f, sn = 0.f;
#pragma unroll
        for (int ni = 0; ni < 4; ++ni) {
          float p = vv[ni] ? __expf(ev[ni] - mloc) : 0.f;  // one exp per entry
          sd += p;
          sn += sv[ni] ? p : 0.f;
        }
#pragma unroll
        for (int m = 8; m >= 1; m >>= 1) {
          sd += __shfl_xor(sd, m);
          sn += __shfl_xor(sn, m);
        }
        if (l15 == 0) {  // one merge per row per wave; disjoint (wc,row) slots
          float mo = stM[wc][row_l];
          float Mn = fmaxf(mo, mloc);            // mloc always finite
          float fo = __expf(mo - Mn);            // -inf start -> 0
          float fn = __expf(mloc - Mn);
          stD[wc][row_l] = stD[wc][row_l] * fo + sd * fn;
          stN[wc][row_l] = stN[wc][row_l] * fo + sn * fn;
          stM[wc][row_l] = Mn;
        }
      }
    }
  }
  __syncthreads();
  if (t < 128) {  // combine the two column-half states, emit chunk partial
    float m0 = stM[0][t], m1 = stM[1][t];
    float M = fmaxf(m0, m1);
    float f0 = __expf(m0 - M), f1 = __expf(m1 - M);
    float4 o;
    o.x = M;
    o.y = stD[0][t] * f0 + stD[1][t] * f1;
    o.z = stN[0][t] * f0 + stN[1][t] * f1;
    o.w = 0.f;
    ((float4*)part)[(size_t)(r0 + t) * NCHUNK + chunk] = o;
  }
}

// ---------------- final: merge chunk partials, mean(den - num) ----------------
__global__ __launch_bounds__(256) void snn_final(const float* __restrict__ part,
                                                 float* __restrict__ out) {
  __shared__ float red[256];
  const int t = threadIdx.x;
  float local = 0.f;
  for (int row = t; row < BN; row += 256) {
    float M = -__builtin_inff(), sd = 0.f, sn = 0.f;
#pragma unroll
    for (int c = 0; c < NCHUNK; ++c) {
      float4 p = ((const float4*)part)[(size_t)row * NCHUNK + c];
      float Mn = fmaxf(M, p.x);
      float fo = expf(M - Mn), fn = expf(p.x - Mn);
      sd = sd * fo + p.y * fn;
      sn = sn * fo + p.z * fn;
      M = Mn;
    }
    float den = M + logf(sd);
    float num = (sn > 0.f) ? (M + logf(sn)) : 0.f;  // isinf(num) -> 0 fixup
    local += den - num;                              // == -(num - den)
  }
  red[t] = local;
  __syncthreads();
  for (int s = 128; s >= 1; s >>= 1) {
    if (t < s) red[t] += red[t + s];
    __syncthreads();
  }
  if (t == 0) out[0] = red[0] * (1.0f / (float)BN);
}

extern "C" void kernel_launch(void* const* d_in, const int* in_sizes, int n_in,
                              void* d_out, int out_size, void* d_ws, size_t ws_size,
                              hipStream_t stream) {
  const float* x = (const float*)d_in[0];
  const int* y = (const int*)d_in[1];
  const unsigned int* Tp = (const unsigned int*)d_in[2];
  float* out = (float*)d_out;

  char* ws = (char*)d_ws;
  unsigned short* xb = (unsigned short*)ws;                       // 16 MB bf16 x
  float* xn = (float*)(ws + (size_t)BN * DK * 2);                 // 32 KB norms
  float* part = (float*)(ws + (size_t)BN * DK * 2 + (size_t)BN * 4);  // 1 MB partials

  snn_prep<<<dim3(BN / 4), dim3(256), 0, stream>>>(x, xb, xn);
  snn_main<<<dim3(NCHUNK, BN / 128), dim3(256), 0, stream>>>(xb, xn, y, Tp, part);
  snn_final<<<dim3(1), dim3(256), 0, stream>>>(part, out);
}

// Round 2
// 150.174 us; speedup vs baseline: 1.9200x; 1.9200x over previous
//
#include <hip/hip_runtime.h>
#include <hip/hip_bf16.h>
#include <stdint.h>

#define BN 8192
#define DK 1024
#define NTILES 2080   // 64*65/2 upper-triangle 128x128 tiles

typedef __attribute__((ext_vector_type(8))) short bf16x8;   // 8 bf16 (4 VGPRs)
typedef __attribute__((ext_vector_type(4))) float f32x4;

__device__ __forceinline__ unsigned short f2bf(float f) {
  unsigned int u = __float_as_uint(f);
  return (unsigned short)((u + 0x7fffu + ((u >> 16) & 1u)) >> 16);
}

// ---------------- prep: bf16 copy of x + fp32 row norms ----------------
__global__ __launch_bounds__(256) void snn_prep(const float* __restrict__ x,
                                                unsigned short* __restrict__ xb,
                                                float* __restrict__ xn) {
  const int row = blockIdx.x * 4 + (threadIdx.x >> 6);
  const int lane = threadIdx.x & 63;
  const float4* src = (const float4*)(x + (size_t)row * DK);
  ushort4* dst = (ushort4*)(xb + (size_t)row * DK);
  float s = 0.f;
#pragma unroll
  for (int i = 0; i < 4; ++i) {
    float4 v = src[lane + i * 64];
    s = fmaf(v.x, v.x, s); s = fmaf(v.y, v.y, s);
    s = fmaf(v.z, v.z, s); s = fmaf(v.w, v.w, s);
    ushort4 o;
    o.x = f2bf(v.x); o.y = f2bf(v.y); o.z = f2bf(v.z); o.w = f2bf(v.w);
    dst[lane + i * 64] = o;
  }
#pragma unroll
  for (int m = 32; m >= 1; m >>= 1) s += __shfl_xor(s, m);
  if (lane == 0) xn[row] = s;
}

// ---------------- main: upper-triangle tiles, fused epilogue ----------------
// grid = 2080 blocks; block 256 (4 waves in 2x2 over a 128x128 tile).
// den[r] += sum_c p(r,c); num[r] += sum_{c same label} p(r,c); p = exp(-dist*T).
// Off-diagonal tiles also emit the transposed (column-side) sums.
__global__ __launch_bounds__(256, 4) void snn_main(
    const unsigned short* __restrict__ xb, const float* __restrict__ xn,
    const int* __restrict__ y, const unsigned int* __restrict__ Tp,
    float* __restrict__ den, float* __restrict__ num) {
  __shared__ __align__(16) unsigned short As[128 * 64];  // XOR-swizzled
  __shared__ __align__(16) unsigned short Bs[128 * 64];
  __shared__ float xnA[128], xnB[128];
  __shared__ int yA[128], yB[128];

  const int t = threadIdx.x;
  const int lane = t & 63;
  const int w = t >> 6;
  const int wr = w >> 1, wc = w & 1;
  const int l15 = lane & 15;
  const int lg = lane >> 4;

  // ---- XCD-chunked swizzle (2080 = 8*260, bijective) + triangle decode ----
  const int bid = blockIdx.x;
  const int ts = (bid & 7) * (NTILES / 8) + (bid >> 3);
  int I = (int)(64.5f - sqrtf(64.5f * 64.5f - 2.0f * (float)ts));
  while (I > 0 && (64 * I - (I * (I - 1)) / 2) > ts) --I;
  while ((64 * (I + 1) - ((I + 1) * I) / 2) <= ts) ++I;
  const int J = I + (ts - (64 * I - (I * (I - 1)) / 2));
  const int r0 = I * 128, c0 = J * 128;
  const bool diag = (I == J);

  const unsigned int tu = *Tp;
  const float tf = (tu & 0x7f800000u) ? __uint_as_float(tu) : (float)(int)tu;

  if (t < 128) {
    xnA[t] = xn[r0 + t]; yA[t] = y[r0 + t];
    xnB[t] = xn[c0 + t]; yB[t] = y[c0 + t];
  }

  f32x4 acc[4][4];
#pragma unroll
  for (int mi = 0; mi < 4; ++mi)
#pragma unroll
    for (int ni = 0; ni < 4; ++ni) acc[mi][ni] = (f32x4){0.f, 0.f, 0.f, 0.f};

  for (int kt = 0; kt < DK; kt += 64) {
    // stage A(128x64), B(128x64); swizzle applied on the GLOBAL source so
    // LDS dest stays linear (global_load_lds requirement).
#pragma unroll
    for (int i = 0; i < 4; ++i) {
      int linear = i * 256 + t;       // 0..1023
      int row = linear >> 3;          // 0..127
      int cg = linear & 7;            // physical 16B chunk
      int cl = cg ^ (row & 7);        // logical chunk
      const unsigned short* sa = xb + (size_t)(r0 + row) * DK + kt + cl * 8;
      const unsigned short* sb = xb + (size_t)(c0 + row) * DK + kt + cl * 8;
      __builtin_amdgcn_global_load_lds(
          (const __attribute__((address_space(1))) void*)sa,
          (__attribute__((address_space(3))) void*)((char*)As + linear * 16),
          16, 0, 0);
      __builtin_amdgcn_global_load_lds(
          (const __attribute__((address_space(1))) void*)sb,
          (__attribute__((address_space(3))) void*)((char*)Bs + linear * 16),
          16, 0, 0);
    }
    __syncthreads();
#pragma unroll
    for (int kk = 0; kk < 2; ++kk) {
      bf16x8 af[4], bfv[4];
      const int colb = kk * 64 + lg * 16;
#pragma unroll
      for (int mi = 0; mi < 4; ++mi) {
        int row = wr * 64 + mi * 16 + l15;
        af[mi] = *(const bf16x8*)((const char*)As + row * 128 +
                                  (colb ^ ((row & 7) << 4)));
      }
#pragma unroll
      for (int ni = 0; ni < 4; ++ni) {
        int row = wc * 64 + ni * 16 + l15;
        bfv[ni] = *(const bf16x8*)((const char*)Bs + row * 128 +
                                   (colb ^ ((row & 7) << 4)));
      }
#pragma unroll
      for (int mi = 0; mi < 4; ++mi)
#pragma unroll
        for (int ni = 0; ni < 4; ++ni)
          acc[mi][ni] = __builtin_amdgcn_mfma_f32_16x16x32_bf16(
              af[mi], bfv[ni], acc[mi][ni], 0, 0, 0);
    }
    __syncthreads();
  }

  // ---- epilogue: v = (same ? -1 : +1) * exp(-sqrt(max(d2,0))*T), in place ----
  // C layout: col = l15 + ni*16 + wc*64; row = lg*4+rg + mi*16 + wr*64
  float cxn[4]; int cy[4];
#pragma unroll
  for (int ni = 0; ni < 4; ++ni) {
    int c_l = wc * 64 + ni * 16 + l15;
    cxn[ni] = xnB[c_l]; cy[ni] = yB[c_l];
  }
#pragma unroll
  for (int mi = 0; mi < 4; ++mi) {
#pragma unroll
    for (int rg = 0; rg < 4; ++rg) {
      const int row_l = wr * 64 + mi * 16 + lg * 4 + rg;
      const int rG = r0 + row_l;
      const float rxn = xnA[row_l];
      const int ry = yA[row_l];
#pragma unroll
      for (int ni = 0; ni < 4; ++ni) {
        const int cG = c0 + wc * 64 + ni * 16 + l15;
        float a = acc[mi][ni][rg];
        float d2 = fmaxf(rxn + cxn[ni] - 2.0f * a, 0.f);
        float p = (rG == cG) ? 0.f : __expf(-sqrtf(d2) * tf);
        acc[mi][ni][rg] = (ry == cy[ni]) ? -p : p;
      }
    }
  }

  // ---- side 1: row sums (rows of tile I over cols of tile J) ----
#pragma unroll
  for (int mi = 0; mi < 4; ++mi) {
#pragma unroll
    for (int rg = 0; rg < 4; ++rg) {
      float u = 0.f, wv = 0.f;
#pragma unroll
      for (int ni = 0; ni < 4; ++ni) {
        float v = acc[mi][ni][rg];
        u += v; wv += fabsf(v);
      }
#pragma unroll
      for (int m = 8; m >= 1; m >>= 1) {
        u += __shfl_xor(u, m); wv += __shfl_xor(wv, m);
      }
      if (l15 == 0) {
        const int rG = r0 + wr * 64 + mi * 16 + lg * 4 + rg;
        atomicAdd(&den[rG], wv);
        atomicAdd(&num[rG], 0.5f * (wv - u));
      }
    }
  }

  // ---- side 2: column sums (rows of tile J over cols of tile I) ----
  if (!diag) {
#pragma unroll
    for (int ni = 0; ni < 4; ++ni) {
      float u = 0.f, wv = 0.f;
#pragma unroll
      for (int mi = 0; mi < 4; ++mi)
#pragma unroll
        for (int rg = 0; rg < 4; ++rg) {
          float v = acc[mi][ni][rg];
          u += v; wv += fabsf(v);
        }
      u += __shfl_xor(u, 16); wv += __shfl_xor(wv, 16);
      u += __shfl_xor(u, 32); wv += __shfl_xor(wv, 32);
      if (lg == 0) {
        const int cG = c0 + wc * 64 + ni * 16 + l15;
        atomicAdd(&den[cG], wv);
        atomicAdd(&num[cG], 0.5f * (wv - u));
      }
    }
  }
}

// ---------------- final: loss = mean(den_log - num_log) ----------------
__global__ __launch_bounds__(256) void snn_final(const float* __restrict__ den,
                                                 const float* __restrict__ num,
                                                 float* __restrict__ out) {
  __shared__ float red[256];
  const int t = threadIdx.x;
  float local = 0.f;
  for (int r = t; r < BN; r += 256) {
    float sd = den[r], sn = num[r];
    float d = logf(sd);
    float n = (sn > 0.f) ? logf(sn) : 0.f;  // no positives -> num = 0 fixup
    local += d - n;
  }
  red[t] = local;
  __syncthreads();
  for (int s = 128; s >= 1; s >>= 1) {
    if (t < s) red[t] += red[t + s];
    __syncthreads();
  }
  if (t == 0) out[0] = red[0] * (1.0f / (float)BN);
}

extern "C" void kernel_launch(void* const* d_in, const int* in_sizes, int n_in,
                              void* d_out, int out_size, void* d_ws, size_t ws_size,
                              hipStream_t stream) {
  const float* x = (const float*)d_in[0];
  const int* y = (const int*)d_in[1];
  const unsigned int* Tp = (const unsigned int*)d_in[2];
  float* out = (float*)d_out;

  char* ws = (char*)d_ws;
  unsigned short* xb = (unsigned short*)ws;                 // 16 MB bf16 x
  float* xn = (float*)(ws + (size_t)BN * DK * 2);           // 32 KB norms
  float* den = xn + BN;                                     // 32 KB
  float* num = den + BN;                                    // 32 KB

  snn_prep<<<dim3(BN / 4), dim3(256), 0, stream>>>(x, xb, xn);
  hipMemsetAsync(den, 0, (size_t)2 * BN * sizeof(float), stream);
  snn_main<<<dim3(NTILES), dim3(256), 0, stream>>>(xb, xn, y, Tp, den, num);
  snn_final<<<dim3(1), dim3(256), 0, stream>>>(den, num, out);
}